// Round 1
// baseline (257.673 us; speedup 1.0000x reference)
//
#include <hip/hip_runtime.h>
#include <hip/hip_bf16.h>
#include <math.h>

typedef __bf16 bf16;
typedef __bf16 bf16x8 __attribute__((ext_vector_type(8)));
typedef __bf16 bf16x4 __attribute__((ext_vector_type(4)));
typedef float floatx4 __attribute__((ext_vector_type(4)));

#define NPIX 4096
#define DCH 256
#define LSTR 72   // padded LDS row stride in bf16 (64 data + 8 pad); 144B, 16B-aligned, bank-rotating

// ---------------- workspace layout (bytes) ----------------
#define OFF_Q   ((size_t)0)                    // bf16 [2][4096][256]   4 MB
#define OFF_K   ((size_t)4194304)              // bf16 [2][4096][256]   4 MB
#define OFF_VT  ((size_t)8388608)              // f32  [2][256][4096]   8 MB  (v transposed)
#define OFF_E   ((size_t)16777216)             // bf16 [4096][4096]     32 MB (per-batch, reused)
#define OFF_VPP ((size_t)50331648)             // bf16 [256][4096]      2 MB  (v'' transposed, per-batch)
#define OFF_PART ((size_t)52428800)            // f32  [4][256][4096]   16 MB (split-K partials)
#define OFF_RS  ((size_t)69206016)             // f32  [2][4096]
#define OFF_CS  ((size_t)69238784)             // f32  [2][4096]

// ============ K1: 1x1 conv (fp32 tiled GEMM) ============
// out[n][o] = sum_c x[b][c][n] * W[o][c] + b[o]
// q = out[:, 0:256]*0.25 (bf16), k = out[:,256:512]*0.25 (bf16), vT[d][n] = out[n][512+d] (f32)
__global__ __launch_bounds__(256) void conv_qkv(
    const float* __restrict__ x, const float* __restrict__ Wm,
    const float* __restrict__ bias,
    bf16* __restrict__ qb, bf16* __restrict__ kb, float* __restrict__ vT)
{
  __shared__ float xs[32][68];
  __shared__ float ws[64][36];
  const int b  = blockIdx.z;
  const int n0 = blockIdx.x * 64;
  const int o0 = blockIdx.y * 64;
  const int t  = threadIdx.x;
  const int tn = t & 15, to = t >> 4;
  const float* xb = x + (size_t)b * DCH * NPIX;
  float acc[4][4];
  for (int j = 0; j < 4; j++) for (int i = 0; i < 4; i++) acc[j][i] = 0.f;

  for (int k0 = 0; k0 < DCH; k0 += 32) {
    for (int i = 0; i < 2; i++) {                 // x tile [32 c][64 n]
      int slot = t + i * 256;
      int c = slot >> 4, n4 = (slot & 15) * 4;
      float4 v = *(const float4*)(xb + (size_t)(k0 + c) * NPIX + n0 + n4);
      xs[c][n4+0] = v.x; xs[c][n4+1] = v.y; xs[c][n4+2] = v.z; xs[c][n4+3] = v.w;
    }
    for (int i = 0; i < 2; i++) {                 // W tile [64 o][32 c]
      int slot = t + i * 256;
      int o = slot >> 3, c4 = (slot & 7) * 4;
      float4 v = *(const float4*)(Wm + (size_t)(o0 + o) * DCH + k0 + c4);
      ws[o][c4+0] = v.x; ws[o][c4+1] = v.y; ws[o][c4+2] = v.z; ws[o][c4+3] = v.w;
    }
    __syncthreads();
    for (int c = 0; c < 32; c++) {
      float4 a4 = *(const float4*)&xs[c][tn*4];
      float a[4] = {a4.x, a4.y, a4.z, a4.w};
      float w[4];
      for (int j = 0; j < 4; j++) w[j] = ws[to*4+j][c];
      for (int j = 0; j < 4; j++)
        for (int i = 0; i < 4; i++) acc[j][i] += a[i] * w[j];
    }
    __syncthreads();
  }

  if (o0 < 512) {   // q or k: pack 4 bf16 along o
    bf16* dst = (o0 < 256) ? qb : kb;
    int obase = (o0 < 256) ? o0 : (o0 - 256);
    for (int i = 0; i < 4; i++) {
      int n = n0 + tn*4 + i;
      bf16x4 pk;
      for (int j = 0; j < 4; j++)
        pk[j] = (bf16)((acc[j][i] + bias[o0 + to*4 + j]) * 0.25f);
      *(bf16x4*)(dst + ((size_t)b * NPIX + n) * DCH + obase + to*4) = pk;
    }
  } else {          // v: write transposed vT[d][n], float4 along n
    for (int j = 0; j < 4; j++) {
      int d = o0 - 512 + to*4 + j;
      float bo = bias[o0 + to*4 + j];
      float4 fv = { acc[j][0]+bo, acc[j][1]+bo, acc[j][2]+bo, acc[j][3]+bo };
      *(float4*)(vT + ((size_t)b * DCH + d) * NPIX + n0 + tn*4) = fv;
    }
  }
}

// ============ K2: pass A — E = exp(q kᵀ), rowsum ============
// D = K_tile · Q_tileᵀ so lane's 4 acc values are consecutive in m (contiguous E store).
__global__ __launch_bounds__(256) void pass_a(
    const bf16* __restrict__ qb, const bf16* __restrict__ kb,
    bf16* __restrict__ E, float* __restrict__ rowsum)
{
  __shared__ bf16 kt[128 * LSTR];
  __shared__ bf16 qt[128 * LSTR];
  __shared__ float rowpart[128];
  const int t  = threadIdx.x;
  const int m0 = blockIdx.x * 128;
  const int n0 = blockIdx.y * 128;
  const int lane = t & 63, wave = t >> 6;
  const int wm = wave >> 1, wn = wave & 1;
  const int l15 = lane & 15, quad = lane >> 4;

  floatx4 acc[4][4];
  for (int i=0;i<4;i++) for (int j=0;j<4;j++) for (int r=0;r<4;r++) acc[i][j][r] = 0.f;

  for (int k0 = 0; k0 < DCH; k0 += 64) {
    for (int i = 0; i < 4; i++) {
      int slot = t + i*256; int row = slot >> 3, ch = slot & 7;
      *(bf16x8*)&kt[row*LSTR + ch*8] = *(const bf16x8*)(kb + (size_t)(m0+row)*DCH + k0 + ch*8);
    }
    for (int i = 0; i < 4; i++) {
      int slot = t + i*256; int row = slot >> 3, ch = slot & 7;
      *(bf16x8*)&qt[row*LSTR + ch*8] = *(const bf16x8*)(qb + (size_t)(n0+row)*DCH + k0 + ch*8);
    }
    __syncthreads();
    for (int kk = 0; kk < 2; kk++) {
      bf16x8 af[4], bfr[4];
      for (int f = 0; f < 4; f++)
        af[f]  = *(const bf16x8*)&kt[(wm*64 + f*16 + l15)*LSTR + kk*32 + quad*8];
      for (int f = 0; f < 4; f++)
        bfr[f] = *(const bf16x8*)&qt[(wn*64 + f*16 + l15)*LSTR + kk*32 + quad*8];
      for (int fm = 0; fm < 4; fm++)
        for (int fn = 0; fn < 4; fn++)
          acc[fm][fn] = __builtin_amdgcn_mfma_f32_16x16x32_bf16(af[fm], bfr[fn], acc[fm][fn], 0, 0, 0);
    }
    __syncthreads();
  }

  if (t < 128) rowpart[t] = 0.f;
  __syncthreads();

  float rsum[4] = {0.f, 0.f, 0.f, 0.f};
  for (int fm = 0; fm < 4; fm++)
    for (int fn = 0; fn < 4; fn++) {
      int n_g = n0 + wn*64 + fn*16 + l15;
      int m_g = m0 + wm*64 + fm*16 + quad*4;
      bf16x4 pk;
      float s = 0.f;
      for (int r = 0; r < 4; r++) {
        float e = expf(acc[fm][fn][r]);
        pk[r] = (bf16)e;
        s += e;
      }
      *(bf16x4*)(E + (size_t)n_g * NPIX + m_g) = pk;
      rsum[fn] += s;
    }
  for (int fn = 0; fn < 4; fn++) {
    float s = rsum[fn];
    s += __shfl_xor(s, 16);
    s += __shfl_xor(s, 32);
    if (quad == 0) atomicAdd(&rowpart[wn*64 + fn*16 + l15], s);
  }
  __syncthreads();
  if (t < 128) atomicAdd(&rowsum[n0 + t], rowpart[t]);
}

// ============ K3: column sums of exp(u)·E ============
__global__ __launch_bounds__(256) void col_pass(
    const bf16* __restrict__ E, const float* __restrict__ rowsum,
    float* __restrict__ colsum, float logm)
{
  __shared__ float eus[64];
  const int t = threadIdx.x;
  const int mbase = blockIdx.x * 2048 + t * 8;
  const int nbase = blockIdx.y * 64;
  if (t < 64) eus[t] = expf(logm - logf(rowsum[nbase + t]));
  __syncthreads();
  float acc[8];
  for (int i = 0; i < 8; i++) acc[i] = 0.f;
  for (int r = 0; r < 64; r++) {
    float eu = eus[r];
    bf16x8 ev = *(const bf16x8*)(E + (size_t)(nbase + r) * NPIX + mbase);
    for (int i = 0; i < 8; i++) acc[i] += eu * (float)ev[i];
  }
  for (int i = 0; i < 8; i++) atomicAdd(&colsum[mbase + i], acc[i]);
}

// ============ K4: v''T[d][m] = exp(vpot[m]) * vT[d][m] (bf16) ============
__global__ __launch_bounds__(256) void vpp_kernel(
    const float* __restrict__ vT, const float* __restrict__ colsum,
    bf16* __restrict__ vppT, float logm)
{
  size_t base = ((size_t)blockIdx.x * 256 + threadIdx.x) * 4;
  int m = (int)(base & (NPIX - 1));
  float4 v = *(const float4*)(vT + base);
  bf16x4 pk;
  pk[0] = (bf16)(v.x * expf(logm - logf(colsum[m + 0])));
  pk[1] = (bf16)(v.y * expf(logm - logf(colsum[m + 1])));
  pk[2] = (bf16)(v.z * expf(logm - logf(colsum[m + 2])));
  pk[3] = (bf16)(v.w * expf(logm - logf(colsum[m + 3])));
  *(bf16x4*)(vppT + base) = pk;
}

// ============ K5: pass C — partial[kc][d][n] = exp(u[n]) * (E @ v'')[n][d] ============
__global__ __launch_bounds__(256) void pass_c(
    const bf16* __restrict__ E, const bf16* __restrict__ vppT,
    const float* __restrict__ rowsum, float* __restrict__ part, float logm)
{
  __shared__ bf16 et[128 * LSTR];
  __shared__ bf16 vt[128 * LSTR];
  __shared__ float eus[128];
  const int t  = threadIdx.x;
  const int n0 = blockIdx.x * 128;
  const int d0 = blockIdx.y * 128;
  const int mstart = blockIdx.z * 1024;
  if (t < 128) eus[t] = expf(logm - logf(rowsum[n0 + t]));
  const int lane = t & 63, wave = t >> 6;
  const int wn = wave >> 1, wd = wave & 1;
  const int l15 = lane & 15, quad = lane >> 4;

  floatx4 acc[4][4];
  for (int i=0;i<4;i++) for (int j=0;j<4;j++) for (int r=0;r<4;r++) acc[i][j][r] = 0.f;
  __syncthreads();

  for (int k0 = mstart; k0 < mstart + 1024; k0 += 64) {
    for (int i = 0; i < 4; i++) {
      int slot = t + i*256; int row = slot >> 3, ch = slot & 7;
      *(bf16x8*)&et[row*LSTR + ch*8] = *(const bf16x8*)(E + (size_t)(n0+row)*NPIX + k0 + ch*8);
    }
    for (int i = 0; i < 4; i++) {
      int slot = t + i*256; int row = slot >> 3, ch = slot & 7;
      *(bf16x8*)&vt[row*LSTR + ch*8] = *(const bf16x8*)(vppT + (size_t)(d0+row)*NPIX + k0 + ch*8);
    }
    __syncthreads();
    for (int kk = 0; kk < 2; kk++) {
      bf16x8 af[4], bfr[4];
      for (int f = 0; f < 4; f++)
        af[f]  = *(const bf16x8*)&et[(wn*64 + f*16 + l15)*LSTR + kk*32 + quad*8];
      for (int f = 0; f < 4; f++)
        bfr[f] = *(const bf16x8*)&vt[(wd*64 + f*16 + l15)*LSTR + kk*32 + quad*8];
      for (int fn = 0; fn < 4; fn++)
        for (int fd = 0; fd < 4; fd++)
          acc[fn][fd] = __builtin_amdgcn_mfma_f32_16x16x32_bf16(af[fn], bfr[fd], acc[fn][fd], 0, 0, 0);
    }
    __syncthreads();
  }

  for (int fn = 0; fn < 4; fn++)
    for (int fd = 0; fd < 4; fd++) {
      int d_g = d0 + wd*64 + fd*16 + l15;
      int n_l = wn*64 + fn*16 + quad*4;
      float4 o;
      o.x = acc[fn][fd][0] * eus[n_l + 0];
      o.y = acc[fn][fd][1] * eus[n_l + 1];
      o.z = acc[fn][fd][2] * eus[n_l + 2];
      o.w = acc[fn][fd][3] * eus[n_l + 3];
      *(float4*)(part + ((size_t)blockIdx.z * DCH + d_g) * NPIX + n0 + n_l) = o;
    }
}

// ============ K6: reduce split-K partials → out[b][d][n] ============
__global__ __launch_bounds__(256) void reduce_k(
    const float* __restrict__ part, float* __restrict__ outp)
{
  size_t i4 = ((size_t)blockIdx.x * 256 + threadIdx.x) * 4;
  float4 a = *(const float4*)(part + i4);
  float4 b = *(const float4*)(part + (size_t)1048576 + i4);
  float4 c = *(const float4*)(part + (size_t)2097152 + i4);
  float4 d = *(const float4*)(part + (size_t)3145728 + i4);
  float4 s = { a.x+b.x+c.x+d.x, a.y+b.y+c.y+d.y, a.z+b.z+c.z+d.z, a.w+b.w+c.w+d.w };
  *(float4*)(outp + i4) = s;
}

extern "C" void kernel_launch(void* const* d_in, const int* in_sizes, int n_in,
                              void* d_out, int out_size, void* d_ws, size_t ws_size,
                              hipStream_t stream) {
  (void)in_sizes; (void)n_in; (void)out_size; (void)ws_size;
  const float* x    = (const float*)d_in[0];
  const float* Wm   = (const float*)d_in[1];
  const float* bias = (const float*)d_in[2];
  float* outp = (float*)d_out;
  char* ws = (char*)d_ws;

  bf16*  qb   = (bf16*)(ws + OFF_Q);
  bf16*  kb   = (bf16*)(ws + OFF_K);
  float* vT   = (float*)(ws + OFF_VT);
  bf16*  E    = (bf16*)(ws + OFF_E);
  bf16*  vppT = (bf16*)(ws + OFF_VPP);
  float* part = (float*)(ws + OFF_PART);
  float* rs   = (float*)(ws + OFF_RS);
  float* cs   = (float*)(ws + OFF_CS);

  const float logm = logf(1.0f / 4096.0f + 1e-8f);

  hipMemsetAsync(ws + OFF_RS, 0, 65536, stream);  // rowsum + colsum (both batches)

  conv_qkv<<<dim3(64, 12, 2), 256, 0, stream>>>(x, Wm, bias, qb, kb, vT);

  for (int b = 0; b < 2; b++) {
    const bf16* qbb = qb + (size_t)b * NPIX * DCH;
    const bf16* kbb = kb + (size_t)b * NPIX * DCH;
    float* rsb = rs + b * 4096;
    float* csb = cs + b * 4096;
    pass_a<<<dim3(32, 32), 256, 0, stream>>>(qbb, kbb, E, rsb);
    col_pass<<<dim3(2, 64), 256, 0, stream>>>(E, rsb, csb, logm);
    vpp_kernel<<<1024, 256, 0, stream>>>(vT + (size_t)b * DCH * NPIX, csb, vppT, logm);
    pass_c<<<dim3(32, 2, 4), 256, 0, stream>>>(E, vppT, rsb, part, logm);
    reduce_k<<<1024, 256, 0, stream>>>(part, outp + (size_t)b * DCH * NPIX);
  }
}

// Round 2
// 216.853 us; speedup vs baseline: 1.1882x; 1.1882x over previous
//
#include <hip/hip_runtime.h>
#include <hip/hip_bf16.h>
#include <math.h>

typedef __bf16 bf16;
typedef __bf16 bf16x8 __attribute__((ext_vector_type(8)));
typedef __bf16 bf16x4 __attribute__((ext_vector_type(4)));
typedef float floatx4 __attribute__((ext_vector_type(4)));

#define NPIX 4096
#define DCH 256
#define LSTR 72   // padded LDS row stride in bf16

#define MB ((size_t)1048576)
// ---------------- workspace layout (bytes) ----------------
#define OFF_XB   ((size_t)0)                   // bf16 [8192][256]  4 MB  (x transposed, both batches)
#define OFF_WB   (4*MB)                        // bf16 [768][256]   384 KB
#define OFF_Q    (4*MB + 524288)               // bf16 [8192][256]  4 MB
#define OFF_K    (OFF_Q + 4*MB)                // bf16 [8192][256]  4 MB
#define OFF_V    (OFF_K + 4*MB)                // bf16 [8192][256]  4 MB
#define OFF_E    (OFF_V + 4*MB)                // bf16 [4096][4096] 32 MB (per-batch, reused)
#define OFF_VPP  (OFF_E + 32*MB)               // bf16 [256][4096]  2 MB
#define OFF_PART (OFF_VPP + 2*MB)              // f32  [4][256][4096] 16 MB
#define OFF_RS   (OFF_PART + 16*MB)            // f32 [2][4096]
#define OFF_CS   (OFF_RS + 32768)              // f32 [2][4096]

// ============ K0a: transpose x [b][c][n] -> xb16 [b*4096+n][c] (bf16) ============
__global__ __launch_bounds__(256) void transpose_x(
    const float* __restrict__ x, bf16* __restrict__ xb)
{
  __shared__ float ts[64][65];
  const int t = threadIdx.x;
  const int b = blockIdx.z, n0 = blockIdx.x * 64, c0 = blockIdx.y * 64;
  const float* xp = x + ((size_t)b * DCH + c0) * NPIX + n0;
  for (int i = 0; i < 4; i++) {
    int slot = t + i * 256;
    int c = slot >> 4, nq = (slot & 15) * 4;
    float4 v = *(const float4*)(xp + (size_t)c * NPIX + nq);
    ts[c][nq + 0] = v.x; ts[c][nq + 1] = v.y; ts[c][nq + 2] = v.z; ts[c][nq + 3] = v.w;
  }
  __syncthreads();
  for (int i = 0; i < 2; i++) {
    int slot = t + i * 256;
    int n = slot >> 3, cq = (slot & 7) * 8;
    bf16x8 pk;
    for (int j = 0; j < 8; j++) pk[j] = (bf16)ts[cq + j][n];
    *(bf16x8*)(xb + ((size_t)b * NPIX + n0 + n) * DCH + c0 + cq) = pk;
  }
}

// ============ K0b: W fp32 -> bf16 ============
__global__ __launch_bounds__(256) void convert_w(
    const float* __restrict__ W, bf16* __restrict__ wb)
{
  size_t i = ((size_t)blockIdx.x * 256 + threadIdx.x) * 4;
  float4 v = *(const float4*)(W + i);
  bf16x4 pk = { (bf16)v.x, (bf16)v.y, (bf16)v.z, (bf16)v.w };
  *(bf16x4*)(wb + i) = pk;
}

// ============ K1: 1x1 conv as bf16 MFMA GEMM ============
// out[n][o] = sum_c xb[n][c] * wb[o][c] + bias[o]; q,k scaled by 0.25; all bf16 [n][256]
__global__ __launch_bounds__(256) void conv_mfma(
    const bf16* __restrict__ xb, const bf16* __restrict__ wb,
    const float* __restrict__ bias,
    bf16* __restrict__ qb, bf16* __restrict__ kb, bf16* __restrict__ vb)
{
  __shared__ bf16 at[128 * LSTR];  // W rows (M = o)
  __shared__ bf16 bt[128 * LSTR];  // x rows (N = pixel)
  __shared__ float bs[128];
  const int t  = threadIdx.x;
  const int n0 = blockIdx.x * 128;   // pixel tile in [0,8192)
  const int o0 = blockIdx.y * 128;   // out-channel tile in [0,768)
  if (t < 128) bs[t] = bias[o0 + t];
  const int lane = t & 63, wave = t >> 6;
  const int wm = wave >> 1, wn = wave & 1;
  const int l15 = lane & 15, quad = lane >> 4;

  floatx4 acc[4][4];
  for (int i=0;i<4;i++) for (int j=0;j<4;j++) for (int r=0;r<4;r++) acc[i][j][r] = 0.f;

  for (int k0 = 0; k0 < DCH; k0 += 64) {
    for (int i = 0; i < 4; i++) {
      int slot = t + i*256; int row = slot >> 3, ch = slot & 7;
      *(bf16x8*)&at[row*LSTR + ch*8] = *(const bf16x8*)(wb + (size_t)(o0+row)*DCH + k0 + ch*8);
    }
    for (int i = 0; i < 4; i++) {
      int slot = t + i*256; int row = slot >> 3, ch = slot & 7;
      *(bf16x8*)&bt[row*LSTR + ch*8] = *(const bf16x8*)(xb + (size_t)(n0+row)*DCH + k0 + ch*8);
    }
    __syncthreads();
    for (int kk = 0; kk < 2; kk++) {
      bf16x8 af[4], bfr[4];
      for (int f = 0; f < 4; f++)
        af[f]  = *(const bf16x8*)&at[(wm*64 + f*16 + l15)*LSTR + kk*32 + quad*8];
      for (int f = 0; f < 4; f++)
        bfr[f] = *(const bf16x8*)&bt[(wn*64 + f*16 + l15)*LSTR + kk*32 + quad*8];
      for (int fm = 0; fm < 4; fm++)
        for (int fn = 0; fn < 4; fn++)
          acc[fm][fn] = __builtin_amdgcn_mfma_f32_16x16x32_bf16(af[fm], bfr[fn], acc[fm][fn], 0, 0, 0);
    }
    __syncthreads();
  }

  const float scale = (o0 < 512) ? 0.25f : 1.0f;
  bf16* dst; int od;
  if (o0 < 256)      { dst = qb; od = o0; }
  else if (o0 < 512) { dst = kb; od = o0 - 256; }
  else               { dst = vb; od = o0 - 512; }

  for (int fm = 0; fm < 4; fm++)
    for (int fn = 0; fn < 4; fn++) {
      int o_l = wm*64 + fm*16 + quad*4;          // o within 128-tile (4 consecutive via reg)
      int n_g = n0 + wn*64 + fn*16 + l15;        // global pixel row
      bf16x4 pk;
      for (int r = 0; r < 4; r++)
        pk[r] = (bf16)((acc[fm][fn][r] + bs[o_l + r]) * scale);
      *(bf16x4*)(dst + (size_t)n_g * DCH + od + o_l) = pk;
    }
}

// ============ K2: pass A — E = exp(q k^T), rowsum ============
__global__ __launch_bounds__(256) void pass_a(
    const bf16* __restrict__ qb, const bf16* __restrict__ kb,
    bf16* __restrict__ E, float* __restrict__ rowsum)
{
  __shared__ bf16 kt[128 * LSTR];
  __shared__ bf16 qt[128 * LSTR];
  __shared__ float rowpart[128];
  const int t  = threadIdx.x;
  const int m0 = blockIdx.x * 128;
  const int n0 = blockIdx.y * 128;
  const int lane = t & 63, wave = t >> 6;
  const int wm = wave >> 1, wn = wave & 1;
  const int l15 = lane & 15, quad = lane >> 4;

  floatx4 acc[4][4];
  for (int i=0;i<4;i++) for (int j=0;j<4;j++) for (int r=0;r<4;r++) acc[i][j][r] = 0.f;

  for (int k0 = 0; k0 < DCH; k0 += 64) {
    for (int i = 0; i < 4; i++) {
      int slot = t + i*256; int row = slot >> 3, ch = slot & 7;
      *(bf16x8*)&kt[row*LSTR + ch*8] = *(const bf16x8*)(kb + (size_t)(m0+row)*DCH + k0 + ch*8);
    }
    for (int i = 0; i < 4; i++) {
      int slot = t + i*256; int row = slot >> 3, ch = slot & 7;
      *(bf16x8*)&qt[row*LSTR + ch*8] = *(const bf16x8*)(qb + (size_t)(n0+row)*DCH + k0 + ch*8);
    }
    __syncthreads();
    for (int kk = 0; kk < 2; kk++) {
      bf16x8 af[4], bfr[4];
      for (int f = 0; f < 4; f++)
        af[f]  = *(const bf16x8*)&kt[(wm*64 + f*16 + l15)*LSTR + kk*32 + quad*8];
      for (int f = 0; f < 4; f++)
        bfr[f] = *(const bf16x8*)&qt[(wn*64 + f*16 + l15)*LSTR + kk*32 + quad*8];
      for (int fm = 0; fm < 4; fm++)
        for (int fn = 0; fn < 4; fn++)
          acc[fm][fn] = __builtin_amdgcn_mfma_f32_16x16x32_bf16(af[fm], bfr[fn], acc[fm][fn], 0, 0, 0);
    }
    __syncthreads();
  }

  if (t < 128) rowpart[t] = 0.f;
  __syncthreads();

  float rsum[4] = {0.f, 0.f, 0.f, 0.f};
  for (int fm = 0; fm < 4; fm++)
    for (int fn = 0; fn < 4; fn++) {
      int n_g = n0 + wn*64 + fn*16 + l15;
      int m_g = m0 + wm*64 + fm*16 + quad*4;
      bf16x4 pk;
      float s = 0.f;
      for (int r = 0; r < 4; r++) {
        float e = __expf(acc[fm][fn][r]);
        pk[r] = (bf16)e;
        s += e;
      }
      *(bf16x4*)(E + (size_t)n_g * NPIX + m_g) = pk;
      rsum[fn] += s;
    }
  for (int fn = 0; fn < 4; fn++) {
    float s = rsum[fn];
    s += __shfl_xor(s, 16);
    s += __shfl_xor(s, 32);
    if (quad == 0) atomicAdd(&rowpart[wn*64 + fn*16 + l15], s);
  }
  __syncthreads();
  if (t < 128) atomicAdd(&rowsum[n0 + t], rowpart[t]);
}

// ============ K3: column sums of exp(u)·E ============
__global__ __launch_bounds__(256) void col_pass(
    const bf16* __restrict__ E, const float* __restrict__ rowsum,
    float* __restrict__ colsum, float logm)
{
  __shared__ float eus[32];
  const int t = threadIdx.x;
  const int col = blockIdx.x * 1024 + t * 4;
  const int nbase = blockIdx.y * 32;
  if (t < 32) eus[t] = __expf(logm - __logf(rowsum[nbase + t]));
  __syncthreads();
  float acc[4] = {0.f, 0.f, 0.f, 0.f};
  for (int r = 0; r < 32; r++) {
    float eu = eus[r];
    bf16x4 ev = *(const bf16x4*)(E + (size_t)(nbase + r) * NPIX + col);
    for (int i = 0; i < 4; i++) acc[i] += eu * (float)ev[i];
  }
  for (int i = 0; i < 4; i++) atomicAdd(&colsum[col + i], acc[i]);
}

// ============ K4: v''T[d][m] = exp(vpot[m]) * v[m][d]  (transpose + scale) ============
__global__ __launch_bounds__(256) void vpp_kernel(
    const bf16* __restrict__ vb, const float* __restrict__ colsum,
    bf16* __restrict__ vppT, float logm)
{
  __shared__ float ts[64][65];
  __shared__ float ef[64];
  const int t = threadIdx.x;
  const int m0 = blockIdx.x * 64, d0 = blockIdx.y * 64;
  if (t < 64) ef[t] = __expf(logm - __logf(colsum[m0 + t]));
  __syncthreads();
  for (int i = 0; i < 2; i++) {
    int slot = t + i * 256;
    int m = slot >> 3, dq = (slot & 7) * 8;
    bf16x8 v = *(const bf16x8*)(vb + (size_t)(m0 + m) * DCH + d0 + dq);
    float s = ef[m];
    for (int j = 0; j < 8; j++) ts[dq + j][m] = s * (float)v[j];
  }
  __syncthreads();
  for (int i = 0; i < 2; i++) {
    int slot = t + i * 256;
    int d = slot >> 3, mq = (slot & 7) * 8;
    bf16x8 pk;
    for (int j = 0; j < 8; j++) pk[j] = (bf16)ts[d][mq + j];
    *(bf16x8*)(vppT + (size_t)(d0 + d) * NPIX + m0 + mq) = pk;
  }
}

// ============ K5: pass C — partial[kc][d][n] = exp(u[n]) * (E @ v'')[n][d] ============
__global__ __launch_bounds__(256) void pass_c(
    const bf16* __restrict__ E, const bf16* __restrict__ vppT,
    const float* __restrict__ rowsum, float* __restrict__ part, float logm)
{
  __shared__ bf16 et[128 * LSTR];
  __shared__ bf16 vt[128 * LSTR];
  __shared__ float eus[128];
  const int t  = threadIdx.x;
  const int n0 = blockIdx.x * 128;
  const int d0 = blockIdx.y * 128;
  const int mstart = blockIdx.z * 1024;
  if (t < 128) eus[t] = __expf(logm - __logf(rowsum[n0 + t]));
  const int lane = t & 63, wave = t >> 6;
  const int wn = wave >> 1, wd = wave & 1;
  const int l15 = lane & 15, quad = lane >> 4;

  floatx4 acc[4][4];
  for (int i=0;i<4;i++) for (int j=0;j<4;j++) for (int r=0;r<4;r++) acc[i][j][r] = 0.f;
  __syncthreads();

  for (int k0 = mstart; k0 < mstart + 1024; k0 += 64) {
    for (int i = 0; i < 4; i++) {
      int slot = t + i*256; int row = slot >> 3, ch = slot & 7;
      *(bf16x8*)&et[row*LSTR + ch*8] = *(const bf16x8*)(E + (size_t)(n0+row)*NPIX + k0 + ch*8);
    }
    for (int i = 0; i < 4; i++) {
      int slot = t + i*256; int row = slot >> 3, ch = slot & 7;
      *(bf16x8*)&vt[row*LSTR + ch*8] = *(const bf16x8*)(vppT + (size_t)(d0+row)*NPIX + k0 + ch*8);
    }
    __syncthreads();
    for (int kk = 0; kk < 2; kk++) {
      bf16x8 af[4], bfr[4];
      for (int f = 0; f < 4; f++)
        af[f]  = *(const bf16x8*)&et[(wn*64 + f*16 + l15)*LSTR + kk*32 + quad*8];
      for (int f = 0; f < 4; f++)
        bfr[f] = *(const bf16x8*)&vt[(wd*64 + f*16 + l15)*LSTR + kk*32 + quad*8];
      for (int fn = 0; fn < 4; fn++)
        for (int fd = 0; fd < 4; fd++)
          acc[fn][fd] = __builtin_amdgcn_mfma_f32_16x16x32_bf16(af[fn], bfr[fd], acc[fn][fd], 0, 0, 0);
    }
    __syncthreads();
  }

  for (int fn = 0; fn < 4; fn++)
    for (int fd = 0; fd < 4; fd++) {
      int d_g = d0 + wd*64 + fd*16 + l15;
      int n_l = wn*64 + fn*16 + quad*4;
      float4 o;
      o.x = acc[fn][fd][0] * eus[n_l + 0];
      o.y = acc[fn][fd][1] * eus[n_l + 1];
      o.z = acc[fn][fd][2] * eus[n_l + 2];
      o.w = acc[fn][fd][3] * eus[n_l + 3];
      *(float4*)(part + ((size_t)blockIdx.z * DCH + d_g) * NPIX + n0 + n_l) = o;
    }
}

// ============ K6: reduce split-K partials ============
__global__ __launch_bounds__(256) void reduce_k(
    const float* __restrict__ part, float* __restrict__ outp)
{
  size_t i4 = ((size_t)blockIdx.x * 256 + threadIdx.x) * 4;
  float4 a = *(const float4*)(part + i4);
  float4 b = *(const float4*)(part + (size_t)1048576 + i4);
  float4 c = *(const float4*)(part + (size_t)2097152 + i4);
  float4 d = *(const float4*)(part + (size_t)3145728 + i4);
  float4 s = { a.x+b.x+c.x+d.x, a.y+b.y+c.y+d.y, a.z+b.z+c.z+d.z, a.w+b.w+c.w+d.w };
  *(float4*)(outp + i4) = s;
}

extern "C" void kernel_launch(void* const* d_in, const int* in_sizes, int n_in,
                              void* d_out, int out_size, void* d_ws, size_t ws_size,
                              hipStream_t stream) {
  (void)in_sizes; (void)n_in; (void)out_size; (void)ws_size;
  const float* x    = (const float*)d_in[0];
  const float* Wm   = (const float*)d_in[1];
  const float* bias = (const float*)d_in[2];
  float* outp = (float*)d_out;
  char* ws = (char*)d_ws;

  bf16*  xb   = (bf16*)(ws + OFF_XB);
  bf16*  wb   = (bf16*)(ws + OFF_WB);
  bf16*  qb   = (bf16*)(ws + OFF_Q);
  bf16*  kb   = (bf16*)(ws + OFF_K);
  bf16*  vb   = (bf16*)(ws + OFF_V);
  bf16*  E    = (bf16*)(ws + OFF_E);
  bf16*  vppT = (bf16*)(ws + OFF_VPP);
  float* part = (float*)(ws + OFF_PART);
  float* rs   = (float*)(ws + OFF_RS);
  float* cs   = (float*)(ws + OFF_CS);

  const float logm = logf(1.0f / 4096.0f + 1e-8f);

  hipMemsetAsync(ws + OFF_RS, 0, 65536, stream);  // rowsum + colsum (both batches)

  transpose_x<<<dim3(64, 4, 2), 256, 0, stream>>>(x, xb);
  convert_w<<<192, 256, 0, stream>>>(Wm, wb);
  conv_mfma<<<dim3(64, 6), 256, 0, stream>>>(xb, wb, bias, qb, kb, vb);

  for (int b = 0; b < 2; b++) {
    const bf16* qbb = qb + (size_t)b * NPIX * DCH;
    const bf16* kbb = kb + (size_t)b * NPIX * DCH;
    float* rsb = rs + b * 4096;
    float* csb = cs + b * 4096;
    pass_a<<<dim3(32, 32), 256, 0, stream>>>(qbb, kbb, E, rsb);
    col_pass<<<dim3(4, 128), 256, 0, stream>>>(E, rsb, csb, logm);
    vpp_kernel<<<dim3(64, 4), 256, 0, stream>>>(vb + (size_t)b * NPIX * DCH, csb, vppT, logm);
    pass_c<<<dim3(32, 2, 4), 256, 0, stream>>>(E, vppT, rsb, part, logm);
    reduce_k<<<1024, 256, 0, stream>>>(part, outp + (size_t)b * DCH * NPIX);
  }
}

// Round 3
// 183.623 us; speedup vs baseline: 1.4033x; 1.1810x over previous
//
#include <hip/hip_runtime.h>
#include <hip/hip_bf16.h>
#include <math.h>

typedef __bf16 bf16;
typedef __bf16 bf16x8 __attribute__((ext_vector_type(8)));
typedef __bf16 bf16x4 __attribute__((ext_vector_type(4)));
typedef float floatx4 __attribute__((ext_vector_type(4)));

#define NPIX 4096
#define DCH 256
#define LSTR 72   // padded LDS row stride in bf16 (2-way-only bank aliasing => free, m136)

// ---------------- workspace layout (bytes), total ~116 MB of 256 MiB ----------------
#define OFF_XB   ((size_t)0)            // bf16 [8192][256]      4 MB (x transposed, both batches)
#define OFF_WB   ((size_t)4194304)      // bf16 [768][256]       384 KB
#define OFF_Q    ((size_t)4587520)      // bf16 [8192][256]      4 MB
#define OFF_K    ((size_t)8781824)      // bf16 [8192][256]      4 MB
#define OFF_V    ((size_t)12976128)     // bf16 [8192][256]      4 MB
#define OFF_E    ((size_t)17170432)     // bf16 [2][4096][4096]  64 MB (both batches resident)
#define OFF_VPP  ((size_t)84279296)     // bf16 [2][256][4096]   4 MB
#define OFF_PART ((size_t)88473600)     // f32  [2][4][256][4096] 32 MB (split-K partials)
#define OFF_RS   ((size_t)122028032)    // f32 [2][4096]
#define OFF_CS   ((size_t)122060800)    // f32 [2][4096]

// ============ K0a: transpose x [b][c][n] -> xb [b*4096+n][c] (bf16) ============
__global__ __launch_bounds__(256) void transpose_x(
    const float* __restrict__ x, bf16* __restrict__ xb)
{
  __shared__ float ts[64][65];
  const int t = threadIdx.x;
  const int b = blockIdx.z, n0 = blockIdx.x * 64, c0 = blockIdx.y * 64;
  const float* xp = x + ((size_t)b * DCH + c0) * NPIX + n0;
  for (int i = 0; i < 4; i++) {
    int slot = t + i * 256;
    int c = slot >> 4, nq = (slot & 15) * 4;
    float4 v = *(const float4*)(xp + (size_t)c * NPIX + nq);
    ts[c][nq + 0] = v.x; ts[c][nq + 1] = v.y; ts[c][nq + 2] = v.z; ts[c][nq + 3] = v.w;
  }
  __syncthreads();
  for (int i = 0; i < 2; i++) {
    int slot = t + i * 256;
    int n = slot >> 3, cq = (slot & 7) * 8;
    bf16x8 pk;
    for (int j = 0; j < 8; j++) pk[j] = (bf16)ts[cq + j][n];
    *(bf16x8*)(xb + ((size_t)b * NPIX + n0 + n) * DCH + c0 + cq) = pk;
  }
}

// ============ K0b: W fp32 -> bf16 ============
__global__ __launch_bounds__(256) void convert_w(
    const float* __restrict__ W, bf16* __restrict__ wb)
{
  size_t i = ((size_t)blockIdx.x * 256 + threadIdx.x) * 4;
  float4 v = *(const float4*)(W + i);
  bf16x4 pk = { (bf16)v.x, (bf16)v.y, (bf16)v.z, (bf16)v.w };
  *(bf16x4*)(wb + i) = pk;
}

// ============ K1: 1x1 conv as bf16 MFMA GEMM ============
__global__ __launch_bounds__(256) void conv_mfma(
    const bf16* __restrict__ xb, const bf16* __restrict__ wb,
    const float* __restrict__ bias,
    bf16* __restrict__ qb, bf16* __restrict__ kb, bf16* __restrict__ vb)
{
  __shared__ bf16 at[128 * LSTR];
  __shared__ bf16 bt[128 * LSTR];
  __shared__ float bs[128];
  const int t  = threadIdx.x;
  const int n0 = blockIdx.x * 128;   // pixel tile in [0,8192)
  const int o0 = blockIdx.y * 128;   // out-channel tile in [0,768)
  if (t < 128) bs[t] = bias[o0 + t];
  const int lane = t & 63, wave = t >> 6;
  const int wm = wave >> 1, wn = wave & 1;
  const int l15 = lane & 15, quad = lane >> 4;

  floatx4 acc[4][4];
  for (int i=0;i<4;i++) for (int j=0;j<4;j++) for (int r=0;r<4;r++) acc[i][j][r] = 0.f;

  for (int k0 = 0; k0 < DCH; k0 += 64) {
    for (int i = 0; i < 4; i++) {
      int slot = t + i*256; int row = slot >> 3, ch = slot & 7;
      *(bf16x8*)&at[row*LSTR + ch*8] = *(const bf16x8*)(wb + (size_t)(o0+row)*DCH + k0 + ch*8);
    }
    for (int i = 0; i < 4; i++) {
      int slot = t + i*256; int row = slot >> 3, ch = slot & 7;
      *(bf16x8*)&bt[row*LSTR + ch*8] = *(const bf16x8*)(xb + (size_t)(n0+row)*DCH + k0 + ch*8);
    }
    __syncthreads();
    for (int kk = 0; kk < 2; kk++) {
      bf16x8 af[4], bfr[4];
      for (int f = 0; f < 4; f++)
        af[f]  = *(const bf16x8*)&at[(wm*64 + f*16 + l15)*LSTR + kk*32 + quad*8];
      for (int f = 0; f < 4; f++)
        bfr[f] = *(const bf16x8*)&bt[(wn*64 + f*16 + l15)*LSTR + kk*32 + quad*8];
      for (int fm = 0; fm < 4; fm++)
        for (int fn = 0; fn < 4; fn++)
          acc[fm][fn] = __builtin_amdgcn_mfma_f32_16x16x32_bf16(af[fm], bfr[fn], acc[fm][fn], 0, 0, 0);
    }
    __syncthreads();
  }

  const float scale = (o0 < 512) ? 0.25f : 1.0f;
  bf16* dst; int od;
  if (o0 < 256)      { dst = qb; od = o0; }
  else if (o0 < 512) { dst = kb; od = o0 - 256; }
  else               { dst = vb; od = o0 - 512; }

  for (int fm = 0; fm < 4; fm++)
    for (int fn = 0; fn < 4; fn++) {
      int o_l = wm*64 + fm*16 + quad*4;
      int n_g = n0 + wn*64 + fn*16 + l15;
      bf16x4 pk;
      for (int r = 0; r < 4; r++)
        pk[r] = (bf16)((acc[fm][fn][r] + bs[o_l + r]) * scale);
      *(bf16x4*)(dst + (size_t)n_g * DCH + od + o_l) = pk;
    }
}

// ============ K2: pass A — E = exp(q k^T), rowsum; batch = blockIdx.z ============
__global__ __launch_bounds__(256) void pass_a(
    const bf16* __restrict__ qb, const bf16* __restrict__ kb,
    bf16* __restrict__ E, float* __restrict__ rowsum)
{
  __shared__ bf16 kt[128 * LSTR];
  __shared__ bf16 qt[128 * LSTR];
  __shared__ float rowpart[128];
  const int b = blockIdx.z;
  qb += (size_t)b * NPIX * DCH;
  kb += (size_t)b * NPIX * DCH;
  E  += (size_t)b * NPIX * NPIX;
  rowsum += b * NPIX;
  const int t  = threadIdx.x;
  const int m0 = blockIdx.x * 128;
  const int n0 = blockIdx.y * 128;
  const int lane = t & 63, wave = t >> 6;
  const int wm = wave >> 1, wn = wave & 1;
  const int l15 = lane & 15, quad = lane >> 4;

  floatx4 acc[4][4];
  for (int i=0;i<4;i++) for (int j=0;j<4;j++) for (int r=0;r<4;r++) acc[i][j][r] = 0.f;

  for (int k0 = 0; k0 < DCH; k0 += 64) {
    for (int i = 0; i < 4; i++) {
      int slot = t + i*256; int row = slot >> 3, ch = slot & 7;
      *(bf16x8*)&kt[row*LSTR + ch*8] = *(const bf16x8*)(kb + (size_t)(m0+row)*DCH + k0 + ch*8);
    }
    for (int i = 0; i < 4; i++) {
      int slot = t + i*256; int row = slot >> 3, ch = slot & 7;
      *(bf16x8*)&qt[row*LSTR + ch*8] = *(const bf16x8*)(qb + (size_t)(n0+row)*DCH + k0 + ch*8);
    }
    __syncthreads();
    for (int kk = 0; kk < 2; kk++) {
      bf16x8 af[4], bfr[4];
      for (int f = 0; f < 4; f++)
        af[f]  = *(const bf16x8*)&kt[(wm*64 + f*16 + l15)*LSTR + kk*32 + quad*8];
      for (int f = 0; f < 4; f++)
        bfr[f] = *(const bf16x8*)&qt[(wn*64 + f*16 + l15)*LSTR + kk*32 + quad*8];
      for (int fm = 0; fm < 4; fm++)
        for (int fn = 0; fn < 4; fn++)
          acc[fm][fn] = __builtin_amdgcn_mfma_f32_16x16x32_bf16(af[fm], bfr[fn], acc[fm][fn], 0, 0, 0);
    }
    __syncthreads();
  }

  if (t < 128) rowpart[t] = 0.f;
  __syncthreads();

  float rsum[4] = {0.f, 0.f, 0.f, 0.f};
  for (int fm = 0; fm < 4; fm++)
    for (int fn = 0; fn < 4; fn++) {
      int n_g = n0 + wn*64 + fn*16 + l15;
      int m_g = m0 + wm*64 + fm*16 + quad*4;
      bf16x4 pk;
      float s = 0.f;
      for (int r = 0; r < 4; r++) {
        float e = __expf(acc[fm][fn][r]);
        pk[r] = (bf16)e;
        s += e;
      }
      *(bf16x4*)(E + (size_t)n_g * NPIX + m_g) = pk;
      rsum[fn] += s;
    }
  for (int fn = 0; fn < 4; fn++) {
    float s = rsum[fn];
    s += __shfl_xor(s, 16);
    s += __shfl_xor(s, 32);
    if (quad == 0) atomicAdd(&rowpart[wn*64 + fn*16 + l15], s);
  }
  __syncthreads();
  if (t < 128) atomicAdd(&rowsum[n0 + t], rowpart[t]);
}

// ============ K3: column sums of exp(u)·E; batch = blockIdx.z ============
__global__ __launch_bounds__(256) void col_pass(
    const bf16* __restrict__ E, const float* __restrict__ rowsum,
    float* __restrict__ colsum, float logm)
{
  __shared__ float eus[32];
  const int b = blockIdx.z;
  E += (size_t)b * NPIX * NPIX;
  rowsum += b * NPIX;
  colsum += b * NPIX;
  const int t = threadIdx.x;
  const int col = blockIdx.x * 1024 + t * 4;
  const int nbase = blockIdx.y * 32;
  if (t < 32) eus[t] = __expf(logm - __logf(rowsum[nbase + t]));
  __syncthreads();
  float acc[4] = {0.f, 0.f, 0.f, 0.f};
  for (int r = 0; r < 32; r++) {
    float eu = eus[r];
    bf16x4 ev = *(const bf16x4*)(E + (size_t)(nbase + r) * NPIX + col);
    for (int i = 0; i < 4; i++) acc[i] += eu * (float)ev[i];
  }
  for (int i = 0; i < 4; i++) atomicAdd(&colsum[col + i], acc[i]);
}

// ============ K4: v''T[d][m] = exp(vpot[m]) * v[m][d]; batch = blockIdx.z ============
__global__ __launch_bounds__(256) void vpp_kernel(
    const bf16* __restrict__ vb, const float* __restrict__ colsum,
    bf16* __restrict__ vppT, float logm)
{
  __shared__ float ts[64][65];
  __shared__ float ef[64];
  const int b = blockIdx.z;
  vb += (size_t)b * NPIX * DCH;
  colsum += b * NPIX;
  vppT += (size_t)b * DCH * NPIX;
  const int t = threadIdx.x;
  const int m0 = blockIdx.x * 64, d0 = blockIdx.y * 64;
  if (t < 64) ef[t] = __expf(logm - __logf(colsum[m0 + t]));
  __syncthreads();
  for (int i = 0; i < 2; i++) {
    int slot = t + i * 256;
    int m = slot >> 3, dq = (slot & 7) * 8;
    bf16x8 v = *(const bf16x8*)(vb + (size_t)(m0 + m) * DCH + d0 + dq);
    float s = ef[m];
    for (int j = 0; j < 8; j++) ts[dq + j][m] = s * (float)v[j];
  }
  __syncthreads();
  for (int i = 0; i < 2; i++) {
    int slot = t + i * 256;
    int d = slot >> 3, mq = (slot & 7) * 8;
    bf16x8 pk;
    for (int j = 0; j < 8; j++) pk[j] = (bf16)ts[d][mq + j];
    *(bf16x8*)(vppT + (size_t)(d0 + d) * NPIX + m0 + mq) = pk;
  }
}

// ============ K5: pass C — partial[b][kc][d][n] = exp(u[n]) * (E @ v'')[n][d] ============
// blockIdx.z: bit2 = batch, bits 0..1 = split-K chunk
__global__ __launch_bounds__(256) void pass_c(
    const bf16* __restrict__ E, const bf16* __restrict__ vppT,
    const float* __restrict__ rowsum, float* __restrict__ part, float logm)
{
  __shared__ bf16 et[128 * LSTR];
  __shared__ bf16 vt[128 * LSTR];
  __shared__ float eus[128];
  const int z = blockIdx.z;
  const int b = z >> 2, kc = z & 3;
  E += (size_t)b * NPIX * NPIX;
  vppT += (size_t)b * DCH * NPIX;
  rowsum += b * NPIX;
  part += (size_t)(b * 4 + kc) * DCH * NPIX;
  const int t  = threadIdx.x;
  const int n0 = blockIdx.x * 128;
  const int d0 = blockIdx.y * 128;
  const int mstart = kc * 1024;
  if (t < 128) eus[t] = __expf(logm - __logf(rowsum[n0 + t]));
  const int lane = t & 63, wave = t >> 6;
  const int wn = wave >> 1, wd = wave & 1;
  const int l15 = lane & 15, quad = lane >> 4;

  floatx4 acc[4][4];
  for (int i=0;i<4;i++) for (int j=0;j<4;j++) for (int r=0;r<4;r++) acc[i][j][r] = 0.f;
  __syncthreads();

  for (int k0 = mstart; k0 < mstart + 1024; k0 += 64) {
    for (int i = 0; i < 4; i++) {
      int slot = t + i*256; int row = slot >> 3, ch = slot & 7;
      *(bf16x8*)&et[row*LSTR + ch*8] = *(const bf16x8*)(E + (size_t)(n0+row)*NPIX + k0 + ch*8);
    }
    for (int i = 0; i < 4; i++) {
      int slot = t + i*256; int row = slot >> 3, ch = slot & 7;
      *(bf16x8*)&vt[row*LSTR + ch*8] = *(const bf16x8*)(vppT + (size_t)(d0+row)*NPIX + k0 + ch*8);
    }
    __syncthreads();
    for (int kk = 0; kk < 2; kk++) {
      bf16x8 af[4], bfr[4];
      for (int f = 0; f < 4; f++)
        af[f]  = *(const bf16x8*)&et[(wn*64 + f*16 + l15)*LSTR + kk*32 + quad*8];
      for (int f = 0; f < 4; f++)
        bfr[f] = *(const bf16x8*)&vt[(wd*64 + f*16 + l15)*LSTR + kk*32 + quad*8];
      for (int fn = 0; fn < 4; fn++)
        for (int fd = 0; fd < 4; fd++)
          acc[fn][fd] = __builtin_amdgcn_mfma_f32_16x16x32_bf16(af[fn], bfr[fd], acc[fn][fd], 0, 0, 0);
    }
    __syncthreads();
  }

  for (int fn = 0; fn < 4; fn++)
    for (int fd = 0; fd < 4; fd++) {
      int d_g = d0 + wd*64 + fd*16 + l15;
      int n_l = wn*64 + fn*16 + quad*4;
      float4 o;
      o.x = acc[fn][fd][0] * eus[n_l + 0];
      o.y = acc[fn][fd][1] * eus[n_l + 1];
      o.z = acc[fn][fd][2] * eus[n_l + 2];
      o.w = acc[fn][fd][3] * eus[n_l + 3];
      *(float4*)(part + (size_t)d_g * NPIX + n0 + n_l) = o;
    }
}

// ============ K6: reduce split-K partials (both batches) ============
__global__ __launch_bounds__(256) void reduce_k(
    const float* __restrict__ part, float* __restrict__ outp)
{
  size_t i4 = ((size_t)blockIdx.x * 256 + threadIdx.x) * 4;
  size_t b = i4 >> 20;                   // 1048576 f32 per batch output
  size_t off = i4 & (size_t)1048575;
  const float* p = part + b * 4 * (size_t)1048576 + off;
  float4 a = *(const float4*)(p);
  float4 bq = *(const float4*)(p + (size_t)1048576);
  float4 c = *(const float4*)(p + (size_t)2097152);
  float4 d = *(const float4*)(p + (size_t)3145728);
  float4 s = { a.x+bq.x+c.x+d.x, a.y+bq.y+c.y+d.y, a.z+bq.z+c.z+d.z, a.w+bq.w+c.w+d.w };
  *(float4*)(outp + i4) = s;
}

extern "C" void kernel_launch(void* const* d_in, const int* in_sizes, int n_in,
                              void* d_out, int out_size, void* d_ws, size_t ws_size,
                              hipStream_t stream) {
  (void)in_sizes; (void)n_in; (void)out_size; (void)ws_size;
  const float* x    = (const float*)d_in[0];
  const float* Wm   = (const float*)d_in[1];
  const float* bias = (const float*)d_in[2];
  float* outp = (float*)d_out;
  char* ws = (char*)d_ws;

  bf16*  xb   = (bf16*)(ws + OFF_XB);
  bf16*  wb   = (bf16*)(ws + OFF_WB);
  bf16*  qb   = (bf16*)(ws + OFF_Q);
  bf16*  kb   = (bf16*)(ws + OFF_K);
  bf16*  vb   = (bf16*)(ws + OFF_V);
  bf16*  E    = (bf16*)(ws + OFF_E);
  bf16*  vppT = (bf16*)(ws + OFF_VPP);
  float* part = (float*)(ws + OFF_PART);
  float* rs   = (float*)(ws + OFF_RS);
  float* cs   = (float*)(ws + OFF_CS);

  const float logm = logf(1.0f / 4096.0f + 1e-8f);

  hipMemsetAsync(ws + OFF_RS, 0, 65536, stream);  // rowsum + colsum, both batches

  transpose_x<<<dim3(64, 4, 2), 256, 0, stream>>>(x, xb);
  convert_w<<<192, 256, 0, stream>>>(Wm, wb);
  conv_mfma<<<dim3(64, 6), 256, 0, stream>>>(xb, wb, bias, qb, kb, vb);

  pass_a<<<dim3(32, 32, 2), 256, 0, stream>>>(qb, kb, E, rs);
  col_pass<<<dim3(4, 128, 2), 256, 0, stream>>>(E, rs, cs, logm);
  vpp_kernel<<<dim3(64, 4, 2), 256, 0, stream>>>(vb, cs, vppT, logm);
  pass_c<<<dim3(32, 2, 8), 256, 0, stream>>>(E, vppT, rs, part, logm);
  reduce_k<<<2048, 256, 0, stream>>>(part, outp);
}